// Round 3
// baseline (184.084 us; speedup 1.0000x reference)
//
#include <hip/hip_runtime.h>

// FDLT: out[b,m,o] = sum_i psiHat[b,m,i] * E[m][i][o]
//   E[m] = cm * X_parity(m) @ D[m]^T   (X = XFc even m, XFs odd m)
// BATCH=2048, B=128 (m), N=256 (i), O=128 (o)
//
// Kernel 1: Et[m][o][i] (bf16, o-major) into d_ws.
// Kernel 2: 2-phase global_load_lds pipeline. Block = 128(b) x 128(o) at one m,
//           4 waves (each 32b x 128o). A-chunk (128 x 32 f32 = 16 KB) staged
//           async into double-buffered LDS with source-side XOR swizzle
//           (col16 ^= row&7) so ds_read_b128 is conflict-free; B (Et[m],
//           L2-resident) direct to registers.

typedef __attribute__((ext_vector_type(8))) short short8;
typedef __attribute__((ext_vector_type(4))) float f32x4;

#define NBATCH 2048
#define NM 128
#define NI 256   // K dim (i / j)
#define NO 128   // output o dim
#define BK 32    // k-step per stage
#define NT (NI / BK)   // 8 iterations

#define GLB(p) ((const __attribute__((address_space(1))) void*)(p))
#define LDS(p) ((__attribute__((address_space(3))) void*)(p))

__device__ __forceinline__ unsigned short f2bf(float f) {
  // round-to-nearest-even fp32 -> bf16
  unsigned int u = __builtin_bit_cast(unsigned int, f);
  u += 0x7FFFu + ((u >> 16) & 1u);
  return (unsigned short)(u >> 16);
}

__device__ __forceinline__ short8 cvt8(float4 a, float4 b, float s) {
  short8 v;
  v[0] = (short)f2bf(s * a.x); v[1] = (short)f2bf(s * a.y);
  v[2] = (short)f2bf(s * a.z); v[3] = (short)f2bf(s * a.w);
  v[4] = (short)f2bf(s * b.x); v[5] = (short)f2bf(s * b.y);
  v[6] = (short)f2bf(s * b.z); v[7] = (short)f2bf(s * b.w);
  return v;
}

// ---------------- Kernel 1: E precompute ----------------
__global__ __launch_bounds__(256) void e_kernel(
    const float* __restrict__ XFc, const float* __restrict__ XFs,
    const float* __restrict__ D, const float* __restrict__ cmp,
    unsigned short* __restrict__ Et)
{
  const int m = blockIdx.x >> 1;
  const int ihalf = blockIdx.x & 1;
  const int tid = threadIdx.x;
  const int lane = tid & 63;
  const int w = tid >> 6;
  const int lr = lane & 15;   // frag row (A) / col (B)
  const int lg = lane >> 4;   // k group
  const float cm = cmp[0];
  const float* __restrict__ Xp = (m & 1) ? XFs : XFc;
  const float* __restrict__ Dm = D + (size_t)m * (NO * NI);
  const int i0 = ihalf * 128 + w * 32;

  f32x4 acc[2][8];
#pragma unroll
  for (int a = 0; a < 2; a++)
#pragma unroll
    for (int b = 0; b < 8; b++) acc[a][b] = (f32x4)0.f;

  for (int kk = 0; kk < NI; kk += 32) {
    const int kb = kk + lg * 8;
    short8 af[2];
#pragma unroll
    for (int rf = 0; rf < 2; rf++) {
      const float* ap = Xp + (size_t)(i0 + rf * 16 + lr) * NI + kb;
      float4 x0 = *(const float4*)ap;
      float4 x1 = *(const float4*)(ap + 4);
      af[rf] = cvt8(x0, x1, cm);
    }
    short8 bf[8];
#pragma unroll
    for (int cf = 0; cf < 8; cf++) {
      const float* bp = Dm + (size_t)(cf * 16 + lr) * NI + kb;
      float4 x0 = *(const float4*)bp;
      float4 x1 = *(const float4*)(bp + 4);
      bf[cf] = cvt8(x0, x1, 1.0f);
    }
#pragma unroll
    for (int rf = 0; rf < 2; rf++)
#pragma unroll
      for (int cf = 0; cf < 8; cf++)
        acc[rf][cf] = __builtin_amdgcn_mfma_f32_16x16x32_bf16(
            af[rf], bf[cf], acc[rf][cf], 0, 0, 0);
  }

  // C/D layout: col = lane&15 (= o), row = (lane>>4)*4 + reg (= i offset)
  unsigned short* Em = Et + (size_t)m * (NO * NI);
#pragma unroll
  for (int rf = 0; rf < 2; rf++)
#pragma unroll
    for (int cf = 0; cf < 8; cf++) {
      const int i = i0 + rf * 16 + lg * 4;
      const int o = cf * 16 + lr;
      ushort4 pk;
      pk.x = f2bf(acc[rf][cf][0]);
      pk.y = f2bf(acc[rf][cf][1]);
      pk.z = f2bf(acc[rf][cf][2]);
      pk.w = f2bf(acc[rf][cf][3]);
      *(ushort4*)(Em + (size_t)o * NI + i) = pk;
    }
}

// ---------------- Kernel 2: main GEMM, 2-phase async pipeline ----------------
// grid: (2048/128, 128), 256 threads = 4 waves. Block: out[b0..b0+127][m][:].
// LDS A buf: [2][128 rows][32 f32] linear (16 KB each). Swizzle: content at
// phys 16B-slot p of row r is psiHat[...][kk + (p ^ (r&7))*4 ..]; read side
// applies the same XOR. glds dest is linear (base + lane*16), source is
// per-lane pre-swizzled -> both-sides involution (rule #21).
__global__ __launch_bounds__(256, 4) void fdlt_main(
    const float* __restrict__ psiHat,
    const unsigned short* __restrict__ Et,
    float* __restrict__ out)
{
  __shared__ float smem_f[2 * 128 * BK];   // 32 KB
  const int m = blockIdx.y;
  const int tid = threadIdx.x;
  const int lane = tid & 63;
  const int w = tid >> 6;
  const int b0 = blockIdx.x * 128;
  const int lr = lane & 15;
  const int lg = lane >> 4;

  // staging constants (per thread): shot s covers rows s*32 + w*8 + lane/8
  const int st_row_in_w = lane >> 3;              // 0..7
  const int st_co = (lane & 7) ^ st_row_in_w;     // swizzled 16B col slot 0..7
  // global row base for shot s: b0 + s*32 + w*8 + st_row_in_w
  const float* st_src0 = psiHat +
      ((size_t)(b0 + w * 8 + st_row_in_w) * NM + m) * NI + st_co * 4;

  f32x4 acc[2][8];
#pragma unroll
  for (int a = 0; a < 2; a++)
#pragma unroll
    for (int b = 0; b < 8; b++) acc[a][b] = (f32x4)0.f;

  const unsigned short* __restrict__ Em = Et + (size_t)m * (NO * NI);
  char* smem = (char*)smem_f;

  // STAGE(c, t): async-copy A chunk for k-step t into buf c (4 glds/thread)
  auto STAGE = [&](int c, int t) {
#pragma unroll
    for (int s = 0; s < 4; s++) {
      const float* src = st_src0 + (size_t)s * 32 * NM * NI + t * BK;
      void* dst = smem + c * 16384 + s * 4096 + w * 1024;
      __builtin_amdgcn_global_load_lds(GLB(src), LDS(dst), 16, 0, 0);
    }
  };

  STAGE(0, 0);
  __syncthreads();   // vmcnt(0) drain + barrier: buf0 ready

  for (int t = 0; t < NT; t++) {
    const int c = t & 1;
    if (t + 1 < NT) STAGE(c ^ 1, t + 1);   // overlaps with compute below

    // ---- compute buf c (k = t*32 .. +31) ----
    const char* Ab = smem + c * 16384;
    short8 af[2];
#pragma unroll
    for (int rf = 0; rf < 2; rf++) {
      const int row = w * 32 + rf * 16 + lr;
      const int sw = lr & 7;                 // == row & 7
      const int s0 = (lg * 2) ^ sw;
      const int s1 = (lg * 2 + 1) ^ sw;
      float4 x0 = *(const float4*)(Ab + row * 128 + s0 * 16);
      float4 x1 = *(const float4*)(Ab + row * 128 + s1 * 16);
      af[rf] = cvt8(x0, x1, 1.0f);
    }
    const int kb = t * BK + lg * 8;
    short8 bf[8];
#pragma unroll
    for (int cf = 0; cf < 8; cf++)
      bf[cf] = *(const short8*)(Em + (size_t)(cf * 16 + lr) * NI + kb);
#pragma unroll
    for (int rf = 0; rf < 2; rf++)
#pragma unroll
      for (int cf = 0; cf < 8; cf++)
        acc[rf][cf] = __builtin_amdgcn_mfma_f32_16x16x32_bf16(
            af[rf], bf[cf], acc[rf][cf], 0, 0, 0);

    __syncthreads();   // drain stage(t+1), sync readers before next overwrite
  }

  // out[b][m][o]; C/D: col = lane&15 (= o), row = (lane>>4)*4+reg (= b offset)
#pragma unroll
  for (int rf = 0; rf < 2; rf++)
#pragma unroll
    for (int cf = 0; cf < 8; cf++) {
      const int o = cf * 16 + lr;
#pragma unroll
      for (int r = 0; r < 4; r++) {
        const int b = b0 + w * 32 + rf * 16 + lg * 4 + r;
        out[((size_t)b * NM + m) * NO + o] = acc[rf][cf][r];
      }
    }
}

extern "C" void kernel_launch(void* const* d_in, const int* in_sizes, int n_in,
                              void* d_out, int out_size, void* d_ws, size_t ws_size,
                              hipStream_t stream) {
  const float* psiHat = (const float*)d_in[0];
  const float* cm     = (const float*)d_in[1];
  const float* XFc    = (const float*)d_in[2];
  const float* XFs    = (const float*)d_in[3];
  const float* D      = (const float*)d_in[4];
  float* out = (float*)d_out;
  unsigned short* Et = (unsigned short*)d_ws;  // 128*128*256*2 = 8.39 MB

  e_kernel<<<256, 256, 0, stream>>>(XFc, XFs, D, cm, Et);
  fdlt_main<<<dim3(NBATCH / 128, NM), 256, 0, stream>>>(psiHat, Et, out);
}

// Round 4
// 156.209 us; speedup vs baseline: 1.1784x; 1.1784x over previous
//
#include <hip/hip_runtime.h>

// FDLT: out[b,m,o] = sum_i psiHat[b,m,i] * E[m][i][o]
//   E[m] = cm * X_parity(m) @ D[m]^T   (X = XFc even m, XFs odd m)
// BATCH=2048, B=128 (m), N=256 (i), O=128 (o)
//
// Kernel 1: Et[m][o][i] (bf16, o-major) into d_ws.
// Kernel 2: direct-to-register GEMM, no LDS. Two pattern fixes vs r2:
//   (1) grid = (m fastest, b-tile slow): resident blocks span all m over a
//       contiguous b-window -> union of L2 misses is a sliding contiguous
//       window of psiHat/out (DRAM row-buffer friendly), and m%8 pins each
//       Et[m] to one XCD L2.
//   (2) A-loads hoisted per half-K chunk (16 x 16B per lane back-to-back):
//       each psiHat row's lines are fetched temporally together (512B bursts)
//       instead of 128B-per-k-iteration.

typedef __attribute__((ext_vector_type(8))) short short8;
typedef __attribute__((ext_vector_type(4))) float f32x4;

#define NBATCH 2048
#define NM 128
#define NI 256   // K dim (i / j)
#define NO 128   // output o dim

__device__ __forceinline__ unsigned short f2bf(float f) {
  // round-to-nearest-even fp32 -> bf16
  unsigned int u = __builtin_bit_cast(unsigned int, f);
  u += 0x7FFFu + ((u >> 16) & 1u);
  return (unsigned short)(u >> 16);
}

__device__ __forceinline__ short8 cvt8(float4 a, float4 b, float s) {
  short8 v;
  v[0] = (short)f2bf(s * a.x); v[1] = (short)f2bf(s * a.y);
  v[2] = (short)f2bf(s * a.z); v[3] = (short)f2bf(s * a.w);
  v[4] = (short)f2bf(s * b.x); v[5] = (short)f2bf(s * b.y);
  v[6] = (short)f2bf(s * b.z); v[7] = (short)f2bf(s * b.w);
  return v;
}

// ---------------- Kernel 1: E precompute ----------------
__global__ __launch_bounds__(256) void e_kernel(
    const float* __restrict__ XFc, const float* __restrict__ XFs,
    const float* __restrict__ D, const float* __restrict__ cmp,
    unsigned short* __restrict__ Et)
{
  const int m = blockIdx.x >> 1;
  const int ihalf = blockIdx.x & 1;
  const int tid = threadIdx.x;
  const int lane = tid & 63;
  const int w = tid >> 6;
  const int lr = lane & 15;   // frag row (A) / col (B)
  const int lg = lane >> 4;   // k group
  const float cm = cmp[0];
  const float* __restrict__ Xp = (m & 1) ? XFs : XFc;
  const float* __restrict__ Dm = D + (size_t)m * (NO * NI);
  const int i0 = ihalf * 128 + w * 32;

  f32x4 acc[2][8];
#pragma unroll
  for (int a = 0; a < 2; a++)
#pragma unroll
    for (int b = 0; b < 8; b++) acc[a][b] = (f32x4)0.f;

  for (int kk = 0; kk < NI; kk += 32) {
    const int kb = kk + lg * 8;
    short8 af[2];
#pragma unroll
    for (int rf = 0; rf < 2; rf++) {
      const float* ap = Xp + (size_t)(i0 + rf * 16 + lr) * NI + kb;
      float4 x0 = *(const float4*)ap;
      float4 x1 = *(const float4*)(ap + 4);
      af[rf] = cvt8(x0, x1, cm);
    }
    short8 bf[8];
#pragma unroll
    for (int cf = 0; cf < 8; cf++) {
      const float* bp = Dm + (size_t)(cf * 16 + lr) * NI + kb;
      float4 x0 = *(const float4*)bp;
      float4 x1 = *(const float4*)(bp + 4);
      bf[cf] = cvt8(x0, x1, 1.0f);
    }
#pragma unroll
    for (int rf = 0; rf < 2; rf++)
#pragma unroll
      for (int cf = 0; cf < 8; cf++)
        acc[rf][cf] = __builtin_amdgcn_mfma_f32_16x16x32_bf16(
            af[rf], bf[cf], acc[rf][cf], 0, 0, 0);
  }

  // C/D layout: col = lane&15 (= o), row = (lane>>4)*4 + reg (= i offset)
  unsigned short* Em = Et + (size_t)m * (NO * NI);
#pragma unroll
  for (int rf = 0; rf < 2; rf++)
#pragma unroll
    for (int cf = 0; cf < 8; cf++) {
      const int i = i0 + rf * 16 + lg * 4;
      const int o = cf * 16 + lr;
      ushort4 pk;
      pk.x = f2bf(acc[rf][cf][0]);
      pk.y = f2bf(acc[rf][cf][1]);
      pk.z = f2bf(acc[rf][cf][2]);
      pk.w = f2bf(acc[rf][cf][3]);
      *(ushort4*)(Em + (size_t)o * NI + i) = pk;
    }
}

// ---------------- Kernel 2: main GEMM ----------------
// grid: (NM, NBATCH/128) -> m is the FAST grid dim (dispatch-window
// contiguity in b). 256 threads = 4 waves; block = 128(b) x 128(o) at one m,
// wave w owns b-rows b0+w*32 .. +31.
// K processed in 2 half-chunks of 128: all A-loads of a chunk issued
// back-to-back, then 4 k-steps of (B-load + 16 MFMA) per chunk.
__global__ __launch_bounds__(256, 2) void fdlt_main(
    const float* __restrict__ psiHat,
    const unsigned short* __restrict__ Et,
    float* __restrict__ out)
{
  const int m = blockIdx.x;
  const int tid = threadIdx.x;
  const int lane = tid & 63;
  const int w = tid >> 6;
  const int b0 = blockIdx.y * 128 + w * 32;
  const int lr = lane & 15;
  const int lg = lane >> 4;

  f32x4 acc[2][8];
#pragma unroll
  for (int a = 0; a < 2; a++)
#pragma unroll
    for (int b = 0; b < 8; b++) acc[a][b] = (f32x4)0.f;

  const unsigned short* __restrict__ Em = Et + (size_t)m * (NO * NI);
  // per-lane A row bases (row = b0 + rf*16 + lr, slice starts at lg*8)
  const float* arow0 = psiHat + ((size_t)(b0 + lr) * NM + m) * NI + lg * 8;
  const float* arow1 = psiHat + ((size_t)(b0 + 16 + lr) * NM + m) * NI + lg * 8;

#pragma unroll
  for (int half = 0; half < 2; half++) {
    // ---- hoisted A-loads: 16 x float4 per lane, issued back-to-back ----
    float4 xa[2][8];   // [rf][tt*2 + piece]
#pragma unroll
    for (int tt = 0; tt < 4; tt++) {
      const int kb = (half * 4 + tt) * 32;
      xa[0][tt * 2]     = *(const float4*)(arow0 + kb);
      xa[0][tt * 2 + 1] = *(const float4*)(arow0 + kb + 4);
      xa[1][tt * 2]     = *(const float4*)(arow1 + kb);
      xa[1][tt * 2 + 1] = *(const float4*)(arow1 + kb + 4);
    }
    short8 af[2][4];
#pragma unroll
    for (int rf = 0; rf < 2; rf++)
#pragma unroll
      for (int tt = 0; tt < 4; tt++)
        af[rf][tt] = cvt8(xa[rf][tt * 2], xa[rf][tt * 2 + 1], 1.0f);

    // ---- 4 k-steps: B direct from L2 + MFMA ----
#pragma unroll
    for (int tt = 0; tt < 4; tt++) {
      const int kb = (half * 4 + tt) * 32 + lg * 8;
      short8 bf[8];
#pragma unroll
      for (int cf = 0; cf < 8; cf++)
        bf[cf] = *(const short8*)(Em + (size_t)(cf * 16 + lr) * NI + kb);
#pragma unroll
      for (int rf = 0; rf < 2; rf++)
#pragma unroll
        for (int cf = 0; cf < 8; cf++)
          acc[rf][cf] = __builtin_amdgcn_mfma_f32_16x16x32_bf16(
              af[rf][tt], bf[cf], acc[rf][cf], 0, 0, 0);
    }
  }

  // out[b][m][o]; C/D: col = lane&15 (= o), row = (lane>>4)*4+reg (= b offset)
#pragma unroll
  for (int rf = 0; rf < 2; rf++)
#pragma unroll
    for (int cf = 0; cf < 8; cf++) {
      const int o = cf * 16 + lr;
#pragma unroll
      for (int r = 0; r < 4; r++) {
        const int b = b0 + rf * 16 + lg * 4 + r;
        out[((size_t)b * NM + m) * NO + o] = acc[rf][cf][r];
      }
    }
}

extern "C" void kernel_launch(void* const* d_in, const int* in_sizes, int n_in,
                              void* d_out, int out_size, void* d_ws, size_t ws_size,
                              hipStream_t stream) {
  const float* psiHat = (const float*)d_in[0];
  const float* cm     = (const float*)d_in[1];
  const float* XFc    = (const float*)d_in[2];
  const float* XFs    = (const float*)d_in[3];
  const float* D      = (const float*)d_in[4];
  float* out = (float*)d_out;
  unsigned short* Et = (unsigned short*)d_ws;  // 128*128*256*2 = 8.39 MB

  e_kernel<<<256, 256, 0, stream>>>(XFc, XFs, D, cm, Et);
  fdlt_main<<<dim3(NM, NBATCH / 128), 256, 0, stream>>>(psiHat, Et, out);
}

// Round 5
// 119.900 us; speedup vs baseline: 1.5353x; 1.3028x over previous
//
#include <hip/hip_runtime.h>

// FDLT: out[b,m,o] = sum_i psiHat[b,m,i] * E[m][i][o]
//   E[m] = cm * X_parity(m) @ D[m]^T   (X = XFc even m, XFs odd m)
// BATCH=2048, B=128 (m), N=256 (i), O=128 (o)
//
// Kernel 1: e_kernel computes E[m] and writes it in MFMA *fragment-packed*
//   order: Bpack[m][t][cf][lane] (16B per lane) where t = k-step (32 i's),
//   cf = o-group of 16. Main-kernel B-loads become wave-uniform base +
//   lane*16B -> single dense 1KB burst per (t,cf).
// Kernel 2: direct-to-register GEMM. A-loads for each half-K chunk are
//   issued as 16 independent dwordx4 then pinned with sched_barrier(0) so
//   the compiler cannot serialize them (r4: VGPR=72 showed it de-hoisted).

typedef __attribute__((ext_vector_type(8))) short short8;
typedef __attribute__((ext_vector_type(4))) float f32x4;

#define NBATCH 2048
#define NM 128
#define NI 256   // K dim (i / j)
#define NO 128   // output o dim
// Bpack: per m: 8 t-steps x 8 cf x 64 lanes x 8 bf16 = 32768 shorts (64 KB)
#define BPACK_M 32768

__device__ __forceinline__ unsigned short f2bf(float f) {
  // round-to-nearest-even fp32 -> bf16
  unsigned int u = __builtin_bit_cast(unsigned int, f);
  u += 0x7FFFu + ((u >> 16) & 1u);
  return (unsigned short)(u >> 16);
}

__device__ __forceinline__ short8 cvt8(float4 a, float4 b, float s) {
  short8 v;
  v[0] = (short)f2bf(s * a.x); v[1] = (short)f2bf(s * a.y);
  v[2] = (short)f2bf(s * a.z); v[3] = (short)f2bf(s * a.w);
  v[4] = (short)f2bf(s * b.x); v[5] = (short)f2bf(s * b.y);
  v[6] = (short)f2bf(s * b.z); v[7] = (short)f2bf(s * b.w);
  return v;
}

// ---------------- Kernel 1: E precompute -> fragment-packed Bpack ----------
// grid: 256 blocks (m = bx>>1, i-half = bx&1), 256 threads = 4 waves.
// wave computes 32(i) x 128(o); K = j over 256.
__global__ __launch_bounds__(256) void e_kernel(
    const float* __restrict__ XFc, const float* __restrict__ XFs,
    const float* __restrict__ D, const float* __restrict__ cmp,
    unsigned short* __restrict__ Bpack)
{
  const int m = blockIdx.x >> 1;
  const int ihalf = blockIdx.x & 1;
  const int tid = threadIdx.x;
  const int lane = tid & 63;
  const int w = tid >> 6;
  const int lr = lane & 15;   // frag row (A) / col (B)
  const int lg = lane >> 4;   // k group
  const float cm = cmp[0];
  const float* __restrict__ Xp = (m & 1) ? XFs : XFc;
  const float* __restrict__ Dm = D + (size_t)m * (NO * NI);
  const int i0 = ihalf * 128 + w * 32;   // multiple of 32

  f32x4 acc[2][8];
#pragma unroll
  for (int a = 0; a < 2; a++)
#pragma unroll
    for (int b = 0; b < 8; b++) acc[a][b] = (f32x4)0.f;

  for (int kk = 0; kk < NI; kk += 32) {
    const int kb = kk + lg * 8;
    short8 af[2];
#pragma unroll
    for (int rf = 0; rf < 2; rf++) {
      const float* ap = Xp + (size_t)(i0 + rf * 16 + lr) * NI + kb;
      float4 x0 = *(const float4*)ap;
      float4 x1 = *(const float4*)(ap + 4);
      af[rf] = cvt8(x0, x1, cm);
    }
    short8 bf[8];
#pragma unroll
    for (int cf = 0; cf < 8; cf++) {
      const float* bp = Dm + (size_t)(cf * 16 + lr) * NI + kb;
      float4 x0 = *(const float4*)bp;
      float4 x1 = *(const float4*)(bp + 4);
      bf[cf] = cvt8(x0, x1, 1.0f);
    }
#pragma unroll
    for (int rf = 0; rf < 2; rf++)
#pragma unroll
      for (int cf = 0; cf < 8; cf++)
        acc[rf][cf] = __builtin_amdgcn_mfma_f32_16x16x32_bf16(
            af[rf], bf[cf], acc[rf][cf], 0, 0, 0);
  }

  // acc C/D layout: o = cf*16 + lr, i = i0 + rf*16 + lg*4 + reg.
  // Pack for consumer: lane L of (t, cf) holds E[i = t*32 + (L>>4)*8 + j]
  // [o = cf*16 + (L&15)], j=0..7. Our 4 regs are half of one such 8-run:
  //   t = (i0 + rf*16) >> 5, L = ((2*rf + (lg>>1)) & 3)*16 + lr,
  //   j-offset = (lg&1)*4.
  unsigned short* Bm = Bpack + (size_t)m * BPACK_M;
#pragma unroll
  for (int rf = 0; rf < 2; rf++) {
    const int t = (i0 + rf * 16) >> 5;
    const int L = ((2 * rf + (lg >> 1)) & 3) * 16 + lr;
#pragma unroll
    for (int cf = 0; cf < 8; cf++) {
      ushort4 pk;
      pk.x = f2bf(acc[rf][cf][0]);
      pk.y = f2bf(acc[rf][cf][1]);
      pk.z = f2bf(acc[rf][cf][2]);
      pk.w = f2bf(acc[rf][cf][3]);
      *(ushort4*)(Bm + (size_t)(t * 8 + cf) * 512 + L * 8 + (lg & 1) * 4) = pk;
    }
  }
}

// ---------------- Kernel 2: main GEMM ----------------
// grid: (NM, NBATCH/128) -> m is the FAST grid dim. 256 threads = 4 waves;
// block = 128(b) x 128(o) at one m, wave w owns b-rows b0+w*32 .. +31.
// K in 2 half-chunks of 128: 16 A-dwordx4 issued back-to-back, pinned with
// sched_barrier(0), then 4 k-steps of (dense B-load + 16 MFMA).
__global__ __launch_bounds__(256) void fdlt_main(
    const float* __restrict__ psiHat,
    const unsigned short* __restrict__ Bpack,
    float* __restrict__ out)
{
  const int m = blockIdx.x;
  const int tid = threadIdx.x;
  const int lane = tid & 63;
  const int w = tid >> 6;
  const int b0 = blockIdx.y * 128 + w * 32;
  const int lr = lane & 15;
  const int lg = lane >> 4;

  f32x4 acc[2][8];
#pragma unroll
  for (int a = 0; a < 2; a++)
#pragma unroll
    for (int b = 0; b < 8; b++) acc[a][b] = (f32x4)0.f;

  const unsigned short* __restrict__ Bm = Bpack + (size_t)m * BPACK_M;
  // per-lane A row bases (row = b0 + rf*16 + lr, slice starts at lg*8)
  const float* arow0 = psiHat + ((size_t)(b0 + lr) * NM + m) * NI + lg * 8;
  const float* arow1 = psiHat + ((size_t)(b0 + 16 + lr) * NM + m) * NI + lg * 8;

#pragma unroll
  for (int half = 0; half < 2; half++) {
    // ---- 16 independent A-loads, issued back-to-back ----
    float4 xa[16];   // [rf*8 + tt*2 + piece]
#pragma unroll
    for (int tt = 0; tt < 4; tt++) {
      const int kb = (half * 4 + tt) * 32;
      xa[tt * 2]         = *(const float4*)(arow0 + kb);
      xa[tt * 2 + 1]     = *(const float4*)(arow0 + kb + 4);
      xa[8 + tt * 2]     = *(const float4*)(arow1 + kb);
      xa[8 + tt * 2 + 1] = *(const float4*)(arow1 + kb + 4);
    }
    // pin: loads above may not sink below this point
    __builtin_amdgcn_sched_barrier(0);

    short8 af[2][4];
#pragma unroll
    for (int rf = 0; rf < 2; rf++)
#pragma unroll
      for (int tt = 0; tt < 4; tt++)
        af[rf][tt] = cvt8(xa[rf * 8 + tt * 2], xa[rf * 8 + tt * 2 + 1], 1.0f);

    // ---- 4 k-steps: dense packed B + MFMA ----
#pragma unroll
    for (int tt = 0; tt < 4; tt++) {
      const int t = half * 4 + tt;
      short8 bf[8];
#pragma unroll
      for (int cf = 0; cf < 8; cf++)
        bf[cf] = *(const short8*)(Bm + (size_t)(t * 8 + cf) * 512 + lane * 8);
#pragma unroll
      for (int rf = 0; rf < 2; rf++)
#pragma unroll
        for (int cf = 0; cf < 8; cf++)
          acc[rf][cf] = __builtin_amdgcn_mfma_f32_16x16x32_bf16(
              af[rf][tt], bf[cf], acc[rf][cf], 0, 0, 0);
    }
  }

  // out[b][m][o]; C/D: col = lane&15 (= o), row = (lane>>4)*4+reg (= b offset)
#pragma unroll
  for (int rf = 0; rf < 2; rf++)
#pragma unroll
    for (int cf = 0; cf < 8; cf++) {
      const int o = cf * 16 + lr;
#pragma unroll
      for (int r = 0; r < 4; r++) {
        const int b = b0 + rf * 16 + lg * 4 + r;
        out[((size_t)b * NM + m) * NO + o] = acc[rf][cf][r];
      }
    }
}

extern "C" void kernel_launch(void* const* d_in, const int* in_sizes, int n_in,
                              void* d_out, int out_size, void* d_ws, size_t ws_size,
                              hipStream_t stream) {
  const float* psiHat = (const float*)d_in[0];
  const float* cm     = (const float*)d_in[1];
  const float* XFc    = (const float*)d_in[2];
  const float* XFs    = (const float*)d_in[3];
  const float* D      = (const float*)d_in[4];
  float* out = (float*)d_out;
  unsigned short* Bpack = (unsigned short*)d_ws;  // 128*32768*2 = 8.39 MB

  e_kernel<<<256, 256, 0, stream>>>(XFc, XFs, D, cm, Bpack);
  fdlt_main<<<dim3(NM, NBATCH / 128), 256, 0, stream>>>(psiHat, Bpack, out);
}